// Round 2
// baseline (882.837 us; speedup 1.0000x reference)
//
#include <hip/hip_runtime.h>
#include <hip/hip_bf16.h>

#define SEQ   1440
#define DM    512
#define BEFFN 896
#define CIN   14
#define NBAT  64

typedef unsigned int u32;

__device__ __forceinline__ float bf_lo(u32 u) { union { u32 i; float f; } a; a.i = u << 16;          return a.f; }
__device__ __forceinline__ float bf_hi(u32 u) { union { u32 i; float f; } a; a.i = u & 0xFFFF0000u;  return a.f; }

// ---------------------------------------------------------------------------
// dtype probe: bf16 gate rows sum to ~1; fp32 data misread as bf16 does not.
// flag=1 -> all tensors bf16 ; flag=0 -> all tensors fp32
// ---------------------------------------------------------------------------
__global__ void detect_dtype(const void* __restrict__ gates, int* __restrict__ flag)
{
    if (threadIdx.x == 0 && blockIdx.x == 0) {
        const u32* gb = (const u32*)gates;
        float eb = 0.f;
        for (int r = 0; r < 8; ++r) {
            float sb = 0.f;
            for (int k = 0; k < 4; ++k) {
                int idx = r * 4 + k;
                u32 t = gb[idx >> 1];
                sb += (idx & 1) ? bf_hi(t) : bf_lo(t);
            }
            eb += fabsf(sb - 1.f);
        }
        flag[0] = (eb < 0.25f) ? 1 : 0;   // NaN-safe: NaN<0.25f is false -> fp32
    }
}

// ---------------------------------------------------------------------------
// One wave-batch: 64 lanes = 64 rows (lane < NACT active) of scale with
// L rows/beff, row-stride P outputs; computes PO outputs starting at col JB.
// All W/b indices are compile-time -> scalar loads + SALU converts.
// ---------------------------------------------------------------------------
template<int PO, int P, int L, int RB, int JB, int NACT, int BF>
__device__ __forceinline__ void row_batch(const void* __restrict__ x_,
                                          const void* __restrict__ W_,
                                          const void* __restrict__ b_,
                                          float* __restrict__ ylds, int beff)
{
    int lane = threadIdx.x & 63;
    if (lane >= NACT) return;
    int l = RB + lane;

    float acc[PO];
    if (BF) {
        const u32* bb = (const u32*)b_;
#pragma unroll
        for (int j = 0; j < PO; j += 2) {
            u32 t = bb[(JB + j) >> 1];
            acc[j] = bf_lo(t); acc[j + 1] = bf_hi(t);
        }
    } else {
        const float* bb = (const float*)b_;
#pragma unroll
        for (int j = 0; j < PO; ++j) acc[j] = bb[JB + j];
    }

    if (BF) {
        const uint4* xr = (const uint4*)((const __hip_bfloat16*)x_ + ((long long)beff * L + l) * DM);
        const u32*   Wb = (const u32*)W_;
        for (int d = 0; d < DM; d += 8) {
            uint4 v = xr[d >> 3];
            float xv[8];
            xv[0] = bf_lo(v.x); xv[1] = bf_hi(v.x);
            xv[2] = bf_lo(v.y); xv[3] = bf_hi(v.y);
            xv[4] = bf_lo(v.z); xv[5] = bf_hi(v.z);
            xv[6] = bf_lo(v.w); xv[7] = bf_hi(v.w);
#pragma unroll
            for (int j = 0; j < PO; ++j) {
                const u32* wr = Wb + (((JB + j) * DM + d) >> 1);   // uniform -> s_load
                u32 w0 = wr[0], w1 = wr[1], w2 = wr[2], w3 = wr[3];
                acc[j] = fmaf(xv[0], bf_lo(w0), acc[j]);
                acc[j] = fmaf(xv[1], bf_hi(w0), acc[j]);
                acc[j] = fmaf(xv[2], bf_lo(w1), acc[j]);
                acc[j] = fmaf(xv[3], bf_hi(w1), acc[j]);
                acc[j] = fmaf(xv[4], bf_lo(w2), acc[j]);
                acc[j] = fmaf(xv[5], bf_hi(w2), acc[j]);
                acc[j] = fmaf(xv[6], bf_lo(w3), acc[j]);
                acc[j] = fmaf(xv[7], bf_hi(w3), acc[j]);
            }
        }
    } else {
        const float4* xr = (const float4*)((const float*)x_ + ((long long)beff * L + l) * DM);
        const float*  Wf = (const float*)W_;
        for (int d = 0; d < DM; d += 8) {
            float4 a = xr[d >> 2], b = xr[(d >> 2) + 1];
            float xv[8] = { a.x, a.y, a.z, a.w, b.x, b.y, b.z, b.w };
#pragma unroll
            for (int j = 0; j < PO; ++j) {
                const float* wr = Wf + (JB + j) * DM + d;          // uniform -> s_load
#pragma unroll
                for (int u = 0; u < 8; ++u) acc[j] = fmaf(xv[u], wr[u], acc[j]);
            }
        }
    }

    float* yo = ylds + l * P + JB;
#pragma unroll
    for (int j = 0; j < PO; j += 4)
        *(float4*)(yo + j) = make_float4(acc[j], acc[j + 1], acc[j + 2], acc[j + 3]);
}

// ---------------------------------------------------------------------------
// Fused kernel: one block per beff. Phase 1: y[4][1440] into LDS via
// wave-specialized batches. Phase 2: gated log-sum-exp + (B C)S -> B S C.
// ---------------------------------------------------------------------------
__global__ __launch_bounds__(384) void fused_all(
    const void* __restrict__ x0, const void* __restrict__ x1,
    const void* __restrict__ x2, const void* __restrict__ x3,
    const void* __restrict__ W0, const void* __restrict__ W1,
    const void* __restrict__ W2, const void* __restrict__ W3,
    const void* __restrict__ b0, const void* __restrict__ b1,
    const void* __restrict__ b2, const void* __restrict__ b3,
    const void* __restrict__ gates, void* __restrict__ out,
    const int* __restrict__ flag)
{
    __shared__ float ysh[4 * SEQ];     // 23 KB
    const int beff = blockIdx.x;
    const int w = threadIdx.x >> 6;
    const int isbf = flag[0];

    if (isbf) {
        switch (w) {
            case 0: row_batch<24, 24, 60,   0,  0, 60, 1>(x2, W2, b2, ysh + 2 * SEQ, beff); break;
            case 1: row_batch<24, 48, 30,   0,  0, 30, 1>(x3, W3, b3, ysh + 3 * SEQ, beff); break;
            case 2: row_batch<24, 48, 30,   0, 24, 30, 1>(x3, W3, b3, ysh + 3 * SEQ, beff); break;
            case 3: row_batch<16, 16, 90,   0,  0, 64, 1>(x1, W1, b1, ysh + 1 * SEQ, beff);
                    row_batch< 8,  8, 180,  0,  0, 64, 1>(x0, W0, b0, ysh,           beff); break;
            case 4: row_batch<16, 16, 90,  64,  0, 26, 1>(x1, W1, b1, ysh + 1 * SEQ, beff);
                    row_batch< 8,  8, 180, 64,  0, 64, 1>(x0, W0, b0, ysh,           beff); break;
            case 5: row_batch< 8,  8, 180, 128, 0, 52, 1>(x0, W0, b0, ysh,           beff); break;
        }
    } else {
        switch (w) {
            case 0: row_batch<24, 24, 60,   0,  0, 60, 0>(x2, W2, b2, ysh + 2 * SEQ, beff); break;
            case 1: row_batch<24, 48, 30,   0,  0, 30, 0>(x3, W3, b3, ysh + 3 * SEQ, beff); break;
            case 2: row_batch<24, 48, 30,   0, 24, 30, 0>(x3, W3, b3, ysh + 3 * SEQ, beff); break;
            case 3: row_batch<16, 16, 90,   0,  0, 64, 0>(x1, W1, b1, ysh + 1 * SEQ, beff);
                    row_batch< 8,  8, 180,  0,  0, 64, 0>(x0, W0, b0, ysh,           beff); break;
            case 4: row_batch<16, 16, 90,  64,  0, 26, 0>(x1, W1, b1, ysh + 1 * SEQ, beff);
                    row_batch< 8,  8, 180, 64,  0, 64, 0>(x0, W0, b0, ysh,           beff); break;
            case 5: row_batch< 8,  8, 180, 128, 0, 52, 0>(x0, W0, b0, ysh,           beff); break;
        }
    }
    __syncthreads();

    const int Bi = beff / CIN, c = beff % CIN;
    float g0, g1, g2, g3;
    if (isbf) {
        const u32* gg = (const u32*)gates;
        u32 t0 = gg[beff * 2], t1 = gg[beff * 2 + 1];
        g0 = bf_lo(t0); g1 = bf_hi(t0); g2 = bf_lo(t1); g3 = bf_hi(t1);
    } else {
        float4 gv = ((const float4*)gates)[beff];
        g0 = gv.x; g1 = gv.y; g2 = gv.z; g3 = gv.w;
    }

    for (int s = threadIdx.x; s < SEQ; s += 384) {
        float acc = g0 * __expf(ysh[s])
                  + g1 * __expf(ysh[SEQ + s])
                  + g2 * __expf(ysh[2 * SEQ + s])
                  + g3 * __expf(ysh[3 * SEQ + s]);
        if (acc == 0.f) acc = 2.2204460492503131e-16f;   // np.finfo(float64).eps
        float r = __logf(acc);
        long long oi = (long long)(Bi * SEQ + s) * CIN + c;
        if (isbf) ((__hip_bfloat16*)out)[oi] = __float2bfloat16(r);
        else      ((float*)out)[oi] = r;
    }
}

extern "C" void kernel_launch(void* const* d_in, const int* in_sizes, int n_in,
                              void* d_out, int out_size, void* d_ws, size_t ws_size,
                              hipStream_t stream)
{
    // Input resolution by (distinct) flat element counts.
    const void *x[4] = {0,0,0,0}, *W[4] = {0,0,0,0}, *b[4] = {0,0,0,0}, *gates = 0;
    for (int i = 0; i < n_in; ++i) {
        const void* p = d_in[i];
        switch (in_sizes[i]) {
            case 82575360: x[0] = p; break;   // 896*180*512
            case 41287680: x[1] = p; break;   // 896*90*512
            case 27525120: x[2] = p; break;   // 896*60*512
            case 13762560: x[3] = p; break;   // 896*30*512
            case 4096:  W[0] = p; break;      // 8*512
            case 8192:  W[1] = p; break;      // 16*512
            case 12288: W[2] = p; break;      // 24*512
            case 24576: W[3] = p; break;      // 48*512
            case 8:  b[0] = p; break;
            case 16: b[1] = p; break;
            case 24: b[2] = p; break;
            case 48: b[3] = p; break;
            case 3584: gates = p; break;      // 896*4
        }
    }

    int* flag = (int*)d_ws;   // 4 bytes of scratch only

    detect_dtype<<<1, 64, 0, stream>>>(gates, flag);
    fused_all<<<BEFFN, 384, 0, stream>>>(x[0], x[1], x[2], x[3],
                                         W[0], W[1], W[2], W[3],
                                         b[0], b[1], b[2], b[3],
                                         gates, d_out, flag);
}